// Round 1
// baseline (209.539 us; speedup 1.0000x reference)
//
#include <hip/hip_runtime.h>

// GradientInputLayer: B=64, C=2, L=64, N=16, BIN=360//16=22, EPS=1e-5
// x: (64, 2*64^3) f32 in {0,1}; out: (64,2,16,16) f32
//
// ws layout: [0, 262144)      uint8 bin table tab[i*4096 + j*64 + k]
//            [262144, 393216) float g[128*256] accumulator (pair-major)

#define BINS_PAD 80   // real bins are 0..68 (ax,az in 0..4); 69 = flush sentinel

__global__ __launch_bounds__(256)
void bin_table_kernel(unsigned char* __restrict__ tab, float* __restrict__ g) {
    int v = blockIdx.x * 256 + threadIdx.x;          // 0..262143
    int i = v >> 12, j = (v >> 6) & 63, k = v & 63;
    double xc2 = (double)(j * j + k * k);            // x_comp^2
    double zc2 = (double)(i * i + j * j);            // z_comp^2
    double i2  = (double)(i * i);
    double k2  = (double)(k * k);
    // tan^2 of 22/44/66/88 degrees; literals fold at compile time in double.
    const double T1 = 0.4040262258351568  * 0.4040262258351568;
    const double T2 = 0.9656887748070740  * 0.9656887748070740;
    const double T3 = 2.2460367739042161  * 2.2460367739042161;
    const double T4 = 28.636253282915602  * 28.636253282915602;
    // ax = floor(atan2(xc, i)*deg/22) == #{m : xc^2 > i^2 tan^2(22m)} (strict >
    // handles every atan2(0,*) / atan2(*,0) edge case exactly, incl voxel 0)
    int ax = (xc2 > i2 * T1) + (xc2 > i2 * T2) + (xc2 > i2 * T3) + (xc2 > i2 * T4);
    int az = (k2 > zc2 * T1) + (k2 > zc2 * T2) + (k2 > zc2 * T3) + (k2 > zc2 * T4);
    tab[v] = (unsigned char)(ax * 16 + az);
    if (v < 32768) g[v] = 0.0f;                      // zero the accumulator (ws is poisoned)
}

// One wave (64 threads) per block; block = (pair p, i-slab). Each lane run-length
// accumulates (cur_bin, acc) over its 4-consecutive-k chunks, flushing to LDS
// hist only on bin change. x and tab loads are fully coalesced.
__global__ __launch_bounds__(64)
void scatter_kernel(const float4* __restrict__ x4,
                    const unsigned int* __restrict__ tabu,
                    float* __restrict__ g) {
    __shared__ float hist[BINS_PAD];
    int t = threadIdx.x;
    int p = blockIdx.x >> 6;      // (b,c) pair 0..127
    int i = blockIdx.x & 63;      // i-slab 0..63
    hist[t] = 0.0f;
    if (t < BINS_PAD - 64) hist[64 + t] = 0.0f;
    __syncthreads();

    const float4*       xs = x4   + (size_t)p * 65536 + (size_t)i * 1024;
    const unsigned int* ts = tabu + i * 1024;

    int thi = t >> 4;                 // line sub-index 0..3
    int k0  = (t & 15) * 4;           // this lane's k base (lane-constant)
    float kk0 = (float)(k0 * k0);
    float kk1 = (float)((k0 + 1) * (k0 + 1));
    float kk2 = (float)((k0 + 2) * (k0 + 2));
    float kk3 = (float)((k0 + 3) * (k0 + 3));
    int i2 = i * i;

    float acc = 0.0f;
    int   cur = 69;                   // sentinel bin (never produced; stays 0)

    #pragma unroll 4
    for (int m = 0; m < 16; ++m) {
        float4       xv = xs[m * 64 + t];
        unsigned int u  = ts[m * 64 + t];
        int   j   = m * 4 + thi;      // line within slab
        float r2f = (float)(i2 + j * j);
        {   int b = u & 255;
            float val = xv.x * sqrtf(r2f + kk0);
            if (b != cur) { atomicAdd(&hist[cur], acc); cur = b; acc = val; }
            else          { acc += val; } }
        {   int b = (u >> 8) & 255;
            float val = xv.y * sqrtf(r2f + kk1);
            if (b != cur) { atomicAdd(&hist[cur], acc); cur = b; acc = val; }
            else          { acc += val; } }
        {   int b = (u >> 16) & 255;
            float val = xv.z * sqrtf(r2f + kk2);
            if (b != cur) { atomicAdd(&hist[cur], acc); cur = b; acc = val; }
            else          { acc += val; } }
        {   int b = (u >> 24);
            float val = xv.w * sqrtf(r2f + kk3);
            if (b != cur) { atomicAdd(&hist[cur], acc); cur = b; acc = val; }
            else          { acc += val; } }
    }
    atomicAdd(&hist[cur], acc);
    __syncthreads();

    float* gp = g + p * 256;
    for (int idx = t; idx < BINS_PAD; idx += 64) {
        float hv = hist[idx];
        if (hv != 0.0f) atomicAdd(&gp[idx], hv);
    }
}

// Single block: per-channel mean/var over (B, N, N) = 16384 values in double,
// then fused scale/shift write of all 32768 outputs.
__global__ __launch_bounds__(1024)
void norm_kernel(const float* __restrict__ g,
                 const float* __restrict__ gamma,
                 const float* __restrict__ beta,
                 float* __restrict__ out) {
    __shared__ double red[16][4];
    __shared__ float  coef[4];        // sc0, sc1, sh0, sh1
    int t = threadIdx.x;
    float vals[32];
    double s0 = 0.0, s1 = 0.0, q0 = 0.0, q1 = 0.0;
    #pragma unroll
    for (int n = 0; n < 32; ++n) {
        int idx = t + n * 1024;
        float v = g[idx];
        vals[n] = v;
        double vd = (double)v;
        if ((idx >> 8) & 1) { s1 += vd; q1 += vd * vd; }
        else                { s0 += vd; q0 += vd * vd; }
    }
    #pragma unroll
    for (int off = 32; off > 0; off >>= 1) {
        s0 += __shfl_down(s0, off);
        s1 += __shfl_down(s1, off);
        q0 += __shfl_down(q0, off);
        q1 += __shfl_down(q1, off);
    }
    int wave = t >> 6;
    if ((t & 63) == 0) {
        red[wave][0] = s0; red[wave][1] = s1; red[wave][2] = q0; red[wave][3] = q1;
    }
    __syncthreads();
    if (t == 0) {
        double S0 = 0, S1 = 0, Q0 = 0, Q1 = 0;
        for (int w = 0; w < 16; ++w) {
            S0 += red[w][0]; S1 += red[w][1]; Q0 += red[w][2]; Q1 += red[w][3];
        }
        const double inv_n = 1.0 / 16384.0;
        double m0 = S0 * inv_n, m1 = S1 * inv_n;
        double v0 = Q0 * inv_n - m0 * m0;
        double v1 = Q1 * inv_n - m1 * m1;
        double r0 = 1.0 / sqrt(v0 + 1e-5);
        double r1 = 1.0 / sqrt(v1 + 1e-5);
        float g0 = gamma[0], g1 = gamma[1], b0 = beta[0], b1 = beta[1];
        coef[0] = (float)r0 * g0;
        coef[1] = (float)r1 * g1;
        coef[2] = b0 - (float)(m0 * r0) * g0;
        coef[3] = b1 - (float)(m1 * r1) * g1;
    }
    __syncthreads();
    float sc0 = coef[0], sc1 = coef[1], sh0 = coef[2], sh1 = coef[3];
    #pragma unroll
    for (int n = 0; n < 32; ++n) {
        int idx = t + n * 1024;
        int c = (idx >> 8) & 1;
        out[idx] = vals[n] * (c ? sc1 : sc0) + (c ? sh1 : sh0);
    }
}

extern "C" void kernel_launch(void* const* d_in, const int* in_sizes, int n_in,
                              void* d_out, int out_size, void* d_ws, size_t ws_size,
                              hipStream_t stream) {
    const float* x     = (const float*)d_in[0];
    const float* gamma = (const float*)d_in[1];
    const float* beta  = (const float*)d_in[2];
    float* out = (float*)d_out;

    unsigned char* tab = (unsigned char*)d_ws;
    float*         g   = (float*)((char*)d_ws + 262144);

    bin_table_kernel<<<1024, 256, 0, stream>>>(tab, g);
    scatter_kernel<<<8192, 64, 0, stream>>>((const float4*)x, (const unsigned int*)tab, g);
    norm_kernel<<<1, 1024, 0, stream>>>(g, gamma, beta, out);
}

// Round 2
// 208.433 us; speedup vs baseline: 1.0053x; 1.0053x over previous
//
#include <hip/hip_runtime.h>

// GradientInputLayer: B=64, C=2, L=64, N=16, BIN=360//16=22, EPS=1e-5
// x: (64, 2*64^3) f32 in {0,1}; out: (64,2,16,16) f32
//
// ws layout: [0, 262144)      uint8 bin table tab[i*4096 + j*64 + k]
//            [262144, 393216) float g[128*256] accumulator (pair-major, row stride 256)

#define BINS_PAD 80   // real bins are 0..68 (ax,az in 0..4); 69 = flush sentinel

__global__ __launch_bounds__(256)
void bin_table_kernel(unsigned char* __restrict__ tab, float* __restrict__ g) {
    int v = blockIdx.x * 256 + threadIdx.x;          // 0..262143
    int i = v >> 12, j = (v >> 6) & 63, k = v & 63;
    double xc2 = (double)(j * j + k * k);            // x_comp^2
    double zc2 = (double)(i * i + j * j);            // z_comp^2
    double i2  = (double)(i * i);
    double k2  = (double)(k * k);
    // tan^2 of 22/44/66/88 degrees; fold at compile time in double.
    const double T1 = 0.4040262258351568  * 0.4040262258351568;
    const double T2 = 0.9656887748070740  * 0.9656887748070740;
    const double T3 = 2.2460367739042161  * 2.2460367739042161;
    const double T4 = 28.636253282915602  * 28.636253282915602;
    // ax = floor(atan2(xc, i)*deg/22) == #{m : xc^2 > i^2 tan^2(22m)}; strict >
    // handles every atan2(0,*) / atan2(*,0) edge case exactly (verified absmax 0.0).
    int ax = (xc2 > i2 * T1) + (xc2 > i2 * T2) + (xc2 > i2 * T3) + (xc2 > i2 * T4);
    int az = (k2 > zc2 * T1) + (k2 > zc2 * T2) + (k2 > zc2 * T3) + (k2 > zc2 * T4);
    tab[v] = (unsigned char)(ax * 16 + az);
    if (v < 32768) g[v] = 0.0f;                      // zero the accumulator (ws is poisoned)
}

// 256-thread blocks (4 waves). Block = (pair p, group of 4 i-slabs); wave w owns
// slab i. Per-lane run-length accumulation (cur_bin, acc) over 4-consecutive-k
// chunks, flushing to the block-shared LDS hist only on bin change. x and tab
// loads fully coalesced. One global-atomic flush of <=80 bins per block.
__global__ __launch_bounds__(256)
void scatter_kernel(const float4* __restrict__ x4,
                    const unsigned int* __restrict__ tabu,
                    float* __restrict__ g) {
    __shared__ float hist[BINS_PAD];
    int tid = threadIdx.x;
    int p   = blockIdx.x >> 4;               // (b,c) pair 0..127
    int w   = tid >> 6;                      // wave 0..3
    int t   = tid & 63;                      // lane
    int i   = (blockIdx.x & 15) * 4 + w;     // i-slab 0..63
    if (tid < BINS_PAD) hist[tid] = 0.0f;
    __syncthreads();

    const float4*       xs = x4   + (size_t)p * 65536 + (size_t)i * 1024;
    const unsigned int* ts = tabu + i * 1024;

    int thi = t >> 4;                 // j sub-index 0..3
    int k0  = (t & 15) * 4;           // this lane's k base (lane-constant)
    float kk0 = (float)(k0 * k0);
    float kk1 = (float)((k0 + 1) * (k0 + 1));
    float kk2 = (float)((k0 + 2) * (k0 + 2));
    float kk3 = (float)((k0 + 3) * (k0 + 3));
    int i2 = i * i;

    float acc = 0.0f;
    int   cur = 69;                   // sentinel bin (never produced; stays ~0)

    #pragma unroll 4
    for (int m = 0; m < 16; ++m) {
        float4       xv = xs[m * 64 + t];
        unsigned int u  = ts[m * 64 + t];
        int   j   = m * 4 + thi;      // j-line within slab
        float r2f = (float)(i2 + j * j);
        {   int b = u & 255;
            float val = xv.x * sqrtf(r2f + kk0);
            if (b != cur) { atomicAdd(&hist[cur], acc); cur = b; acc = val; }
            else          { acc += val; } }
        {   int b = (u >> 8) & 255;
            float val = xv.y * sqrtf(r2f + kk1);
            if (b != cur) { atomicAdd(&hist[cur], acc); cur = b; acc = val; }
            else          { acc += val; } }
        {   int b = (u >> 16) & 255;
            float val = xv.z * sqrtf(r2f + kk2);
            if (b != cur) { atomicAdd(&hist[cur], acc); cur = b; acc = val; }
            else          { acc += val; } }
        {   int b = (u >> 24);
            float val = xv.w * sqrtf(r2f + kk3);
            if (b != cur) { atomicAdd(&hist[cur], acc); cur = b; acc = val; }
            else          { acc += val; } }
    }
    atomicAdd(&hist[cur], acc);
    __syncthreads();

    if (tid < BINS_PAD) {
        float hv = hist[tid];
        if (hv != 0.0f) atomicAdd(&g[p * 256 + tid], hv);
    }
}

// Single block: per-channel mean/var over (B, N, N) = 16384 values in double,
// then fused scale/shift write of all 32768 outputs.
__global__ __launch_bounds__(1024)
void norm_kernel(const float* __restrict__ g,
                 const float* __restrict__ gamma,
                 const float* __restrict__ beta,
                 float* __restrict__ out) {
    __shared__ double red[16][4];
    __shared__ float  coef[4];        // sc0, sc1, sh0, sh1
    int t = threadIdx.x;
    float vals[32];
    double s0 = 0.0, s1 = 0.0, q0 = 0.0, q1 = 0.0;
    #pragma unroll
    for (int n = 0; n < 32; ++n) {
        int idx = t + n * 1024;
        float v = g[idx];
        vals[n] = v;
        double vd = (double)v;
        if ((idx >> 8) & 1) { s1 += vd; q1 += vd * vd; }
        else                { s0 += vd; q0 += vd * vd; }
    }
    #pragma unroll
    for (int off = 32; off > 0; off >>= 1) {
        s0 += __shfl_down(s0, off);
        s1 += __shfl_down(s1, off);
        q0 += __shfl_down(q0, off);
        q1 += __shfl_down(q1, off);
    }
    int wave = t >> 6;
    if ((t & 63) == 0) {
        red[wave][0] = s0; red[wave][1] = s1; red[wave][2] = q0; red[wave][3] = q1;
    }
    __syncthreads();
    if (t == 0) {
        double S0 = 0, S1 = 0, Q0 = 0, Q1 = 0;
        for (int wv = 0; wv < 16; ++wv) {
            S0 += red[wv][0]; S1 += red[wv][1]; Q0 += red[wv][2]; Q1 += red[wv][3];
        }
        const double inv_n = 1.0 / 16384.0;
        double m0 = S0 * inv_n, m1 = S1 * inv_n;
        double v0 = Q0 * inv_n - m0 * m0;
        double v1 = Q1 * inv_n - m1 * m1;
        double r0 = 1.0 / sqrt(v0 + 1e-5);
        double r1 = 1.0 / sqrt(v1 + 1e-5);
        float g0 = gamma[0], g1 = gamma[1], b0 = beta[0], b1 = beta[1];
        coef[0] = (float)r0 * g0;
        coef[1] = (float)r1 * g1;
        coef[2] = b0 - (float)(m0 * r0) * g0;
        coef[3] = b1 - (float)(m1 * r1) * g1;
    }
    __syncthreads();
    float sc0 = coef[0], sc1 = coef[1], sh0 = coef[2], sh1 = coef[3];
    #pragma unroll
    for (int n = 0; n < 32; ++n) {
        int idx = t + n * 1024;
        int c = (idx >> 8) & 1;
        out[idx] = vals[n] * (c ? sc1 : sc0) + (c ? sh1 : sh0);
    }
}

extern "C" void kernel_launch(void* const* d_in, const int* in_sizes, int n_in,
                              void* d_out, int out_size, void* d_ws, size_t ws_size,
                              hipStream_t stream) {
    const float* x     = (const float*)d_in[0];
    const float* gamma = (const float*)d_in[1];
    const float* beta  = (const float*)d_in[2];
    float* out = (float*)d_out;

    unsigned char* tab = (unsigned char*)d_ws;
    float*         g   = (float*)((char*)d_ws + 262144);

    bin_table_kernel<<<1024, 256, 0, stream>>>(tab, g);
    scatter_kernel<<<2048, 256, 0, stream>>>((const float4*)x, (const unsigned int*)tab, g);
    norm_kernel<<<1, 1024, 0, stream>>>(g, gamma, beta, out);
}